// Round 18
// baseline (42.023 us; speedup 1.0000x reference)
//
#include <hip/hip_runtime.h>

#define H 512
#define W 512
#define BAND 64
#define NBANDS (H / BAND)   // 8
#define NEG_INF (-3.402823466e38f)

__global__ void zero_acc_kernel(double* acc) {
    if (threadIdx.x == 0) acc[0] = 0.0;
}

// R17 structure (best: 34.8us) + R18 change: async HBM prefetch.
// One block per (band of 64 output rows, image, tensor); 512 threads = 8 waves.
// Batches of 16 s-rows; each wave owns TWO rows (slots w, w+8); double-buffered
// hbuf; ONE barrier per batch; (512,4) no-spill; `#pragma unroll 1` outer loop.
// Horizontal 17-max per row, wave-local: suffix q[8] / prefix p[8] in regs,
// all 16 shuffles issued independently, h(8L+k)=max(q_{L-1}[k], m_L, p_{L+1}[k]).
// Vertical 17-max: batch == van Herk segment, per-column arr[16] in registers.
// R18: dur tracked FETCH/1.2TB/s across R13-R17 -> HBM-latency-bound on
// compulsory misses. Fix: each wave issues global_load_lds (fire-and-forget,
// dest = 1KB dummy LDS, NEVER read; races harmless) for the NEXT batch's two
// new raw rows at batch start. This pulls batch b+1's lines into L2/L3 under
// batch b's compute -> real loads next batch hit L2 (~200cyc, hideable).
// No VGPR liveness across barriers (R11/R12 scratch failure impossible here),
// no numeric change. The pre-barrier vmcnt drain completes the prefetch
// (~0.4us) well inside the batch's ~6us compute.
__global__ __launch_bounds__(512, 4) void fused_kernel(const float* __restrict__ in0,
                                                       const float* __restrict__ in1,
                                                       double* __restrict__ acc) {
    const int band = blockIdx.x;
    const int img  = blockIdx.y;
    const float* __restrict__ im = (blockIdx.z ? in1 : in0) + (size_t)img * H * W;

    const int y0 = band * BAND, y1 = y0 + BAND;
    const int jlo_v = y0 - 8;            // first streamed s-row

    __shared__ float hbuf[2][16][W];     // double-buffered h rows (split-half)
    __shared__ float pfdummy[256];       // prefetch sink (never read)
    __shared__ double wsum[8];

    const int tid  = threadIdx.x;
    const int w    = tid >> 6;           // wave id 0..7
    const int lane = tid & 63;
    const int c0   = lane << 3;          // 8 cols per lane
    // split-half position of column tid inside an hbuf row
    const int pos  = ((tid & 4) ? 256 : 0) + ((tid >> 3) << 2) + (tid & 3);

    float accMax = 0.f, accSum = 0.f;
    float arr[16];                       // van Herk: prev-seg suffix / cur h

#define GLDS(gp) __builtin_amdgcn_global_load_lds(                             \
        (const __attribute__((address_space(1))) void*)(gp),                   \
        (__attribute__((address_space(3))) void*)pfdummy, 16, 0, 0)

// One s-row in slot SLOT (0..15) of batch b. j wave-uniform.
#define ROW(SLOT)                                                              \
    {                                                                          \
        const int j = jb + (SLOT);                                             \
        float h[8];                                                            \
        if (j >= 0 && j < H) {                                                 \
            float t[8];                                                        \
            _Pragma("unroll") for (int k = 0; k < 8; ++k) t[k] = 0.f;          \
            _Pragma("unroll") for (int dr = -1; dr <= 1; ++dr) {               \
                const int r = j + dr;                                          \
                if (r >= 0 && r < H) {          /* wave-uniform */             \
                    const float* rp = im + (size_t)r * W + c0;                 \
                    const float4 a  = *(const float4*)rp;                      \
                    const float4 c4 = *(const float4*)(rp + 4);                \
                    t[0] += a.x;  t[1] += a.y;  t[2] += a.z;  t[3] += a.w;     \
                    t[4] += c4.x; t[5] += c4.y; t[6] += c4.z; t[7] += c4.w;    \
                }                                                              \
            }                                                                  \
            float tl = __shfl_up(t[7], 1);   if (lane == 0)  tl = 0.f;         \
            float tr = __shfl_down(t[0], 1); if (lane == 63) tr = 0.f;         \
            float s[8];                                                        \
            s[0] = tl + t[0] + t[1];                                           \
            _Pragma("unroll") for (int k = 1; k < 7; ++k)                      \
                s[k] = t[k - 1] + t[k] + t[k + 1];                             \
            s[7] = t[6] + t[7] + tr;                                           \
            const int rlo = (j - 8 > y0) ? j - 8 : y0;                         \
            const int rhi = (j + 8 < y1 - 1) ? j + 8 : y1 - 1;                 \
            float rowsum = 0.f;                                                \
            _Pragma("unroll") for (int k = 0; k < 8; ++k) {                    \
                const int col = c0 + k;                                        \
                const int wlo = (col - 8 > 0) ? col - 8 : 0;                   \
                const int whi = (col + 8 < W - 1) ? col + 8 : W - 1;           \
                rowsum += s[k] * (float)(whi - wlo + 1);                       \
            }                                                                  \
            accSum += rowsum * ((float)(rhi - rlo + 1) * (1.f / 289.f));       \
            float p[8], qarr[8];                                               \
            p[0] = s[0];                                                       \
            _Pragma("unroll") for (int k = 1; k < 8; ++k)                      \
                p[k] = fmaxf(p[k - 1], s[k]);                                  \
            qarr[7] = s[7];                                                    \
            _Pragma("unroll") for (int k = 6; k >= 0; --k)                     \
                qarr[k] = fmaxf(qarr[k + 1], s[k]);                            \
            const float m = p[7];                                              \
            float qp[8], pn[8];                                                \
            _Pragma("unroll") for (int k = 0; k < 8; ++k)                      \
                qp[k] = __shfl_up(qarr[k], 1);                                 \
            _Pragma("unroll") for (int k = 0; k < 8; ++k)                      \
                pn[k] = __shfl_down(p[k], 1);                                  \
            _Pragma("unroll") for (int k = 0; k < 8; ++k) {                    \
                if (lane == 0)  qp[k] = NEG_INF;                               \
                if (lane == 63) pn[k] = NEG_INF;                               \
                h[k] = fmaxf(fmaxf(qp[k], m), pn[k]);                          \
            }                                                                  \
        } else {                                                               \
            _Pragma("unroll") for (int k = 0; k < 8; ++k) h[k] = NEG_INF;      \
        }                                                                      \
        {                                                                      \
            float* hw = hwbase + (SLOT) * W;                                   \
            *(float4*)&hw[lane << 2]         = make_float4(h[0], h[1], h[2], h[3]); \
            *(float4*)&hw[256 + (lane << 2)] = make_float4(h[4], h[5], h[6], h[7]); \
        }                                                                      \
    }

#pragma unroll 1
    for (int b = 0; b < 5; ++b) {        // 5 batches of 16 s-rows = 80 rows
        const int jb = jlo_v + b * 16;
        float* hwbase = &hbuf[b & 1][0][0];

        // ---- R18: prefetch next batch's 16 new raw rows (jb+17..jb+32) ----
        if (b < 4) {
            const int pr0 = jb + 17 + w;      // wave-uniform rows
            const int pr1 = jb + 25 + w;
            if (pr0 >= 0 && pr0 < H) {
                const float* g = im + (size_t)pr0 * W + (lane << 2);
                GLDS(g);
                GLDS(g + 256);
            }
            if (pr1 >= 0 && pr1 < H) {
                const float* g = im + (size_t)pr1 * W + (lane << 2);
                GLDS(g);
                GLDS(g + 256);
            }
        }

        ROW(w)                            // slot w
        ROW(w + 8)                        // slot w+8 (independent pipeline)
        __syncthreads();                  // the ONLY barrier per batch

        // ---- stage C: vertical van Herk over this 16-row segment ----
        const float* hb = hwbase;
        float Pblk = NEG_INF;
        if (b >= 1) {
#pragma unroll
            for (int r = 0; r < 16; ++r) {
                const float hv = hb[r * W + pos];
                Pblk = fmaxf(Pblk, hv);
                accMax += fmaxf(arr[r], Pblk);
                arr[r] = hv;
            }
        } else {
#pragma unroll
            for (int r = 0; r < 16; ++r) {
                const float hv = hb[r * W + pos];
                Pblk = fmaxf(Pblk, hv);
                arr[r] = hv;
            }
        }
        // segment end: in-place suffix transform arr[r] = max(h[r..15])
#pragma unroll
        for (int rr = 14; rr >= 0; --rr) arr[rr] = fmaxf(arr[rr], arr[rr + 1]);
    }
#undef ROW
#undef GLDS

    // ---- block reduction (values are 9x-scaled; undo once) ----
    double v = ((double)accMax - (double)accSum) * (1.0 / 9.0);
#pragma unroll
    for (int off = 32; off > 0; off >>= 1) v += __shfl_down(v, off, 64);
    if (lane == 0) wsum[w] = v;
    __syncthreads();
    if (tid == 0) {
        double bsum = 0.0;
#pragma unroll
        for (int wv = 0; wv < 8; ++wv) bsum += wsum[wv];
        atomicAdd(acc, bsum);
    }
}

__global__ void finalize_kernel(const double* __restrict__ acc, float* __restrict__ out) {
    if (threadIdx.x == 0) {
        // total pixels across both tensors = 2*32*512*512 = 16777216
        out[0] = (float)(1.0 - acc[0] * (1.0 / 16777216.0));
    }
}

extern "C" void kernel_launch(void* const* d_in, const int* in_sizes, int n_in,
                              void* d_out, int out_size, void* d_ws, size_t ws_size,
                              hipStream_t stream) {
    const float* in0 = (const float*)d_in[0];
    const float* in1 = (const float*)d_in[1];
    float* out = (float*)d_out;
    double* acc = (double*)d_ws;

    zero_acc_kernel<<<1, 64, 0, stream>>>(acc);
    fused_kernel<<<dim3(NBANDS, 32, 2), 512, 0, stream>>>(in0, in1, acc);
    finalize_kernel<<<1, 64, 0, stream>>>(acc, out);
}

// Round 19
// 33.912 us; speedup vs baseline: 1.2392x; 1.2392x over previous
//
#include <hip/hip_runtime.h>

#define H 512
#define W 512
#define BAND 64
#define NBANDS (H / BAND)   // 8
#define NEG_INF (-3.402823466e38f)

__global__ void zero_acc_kernel(double* acc) {
    if (threadIdx.x == 0) acc[0] = 0.0;
}

// R17 structure (best: 34.8us) + R19 change: contiguous row PAIRS per wave.
// One block per (band of 64 output rows, image, tensor); 512 threads = 8 waves.
// Batches of 16 s-rows; each wave owns slots 2w and 2w+1 (CONTIGUOUS pair):
// the pair's raw rows j0-1..j0+2 overlap -> 8 float4 loads (was 12) and the
// 3-row sums share the middle partial (m=v1+v2; t0=v0+m; t1=m+v3: 24 adds,
// was 48). Pair never straddles a virtual/real or H boundary (jlo_v even,
// H even) -> wave-uniform guards hold.
// Per row (wave-local): s = horizontal 3-sum of t via 2 halo shuffles
// (9x-scaled), horizontal 17-max via suffix q[8]/prefix p[8] in regs with all
// 16 shuffles issued independently: h(8L+k) = max(q_{L-1}[k], m_L, p_{L+1}[k]).
// Vertical 17-max: batch == van Herk segment: publish h rows to
// double-buffered hbuf (ONE barrier per batch), per-column register van Herk
// (arr[16], suffix transform at batch end).
// Lessons: (R12/R13) unroll hoisting + tight VGPR cap -> spill; use
// `#pragma unroll 1` outer loop + (512,4). (R16) single-buffer/extra barrier
// regressed. (R18) dummy-LDS prefetch duplicated FETCH (41->66MB) and the
// pre-barrier vmcnt drain serialized it -> reverted.
// hbuf split-half layout: k=0..3 at [4L], k=4..7 at [256+4L]; writes and
// column reads conflict-free (the ~786K SQ_LDS_BANK_CONFLICT is ds_permute
// shuffle bookkeeping, not a layout bug).
__global__ __launch_bounds__(512, 4) void fused_kernel(const float* __restrict__ in0,
                                                       const float* __restrict__ in1,
                                                       double* __restrict__ acc) {
    const int band = blockIdx.x;
    const int img  = blockIdx.y;
    const float* __restrict__ im = (blockIdx.z ? in1 : in0) + (size_t)img * H * W;

    const int y0 = band * BAND, y1 = y0 + BAND;
    const int jlo_v = y0 - 8;            // first streamed s-row (even)

    __shared__ float hbuf[2][16][W];     // double-buffered h rows (split-half)
    __shared__ double wsum[8];

    const int tid  = threadIdx.x;
    const int w    = tid >> 6;           // wave id 0..7
    const int lane = tid & 63;
    const int c0   = lane << 3;          // 8 cols per lane
    // split-half position of column tid inside an hbuf row
    const int pos  = ((tid & 4) ? 256 : 0) + ((tid >> 3) << 2) + (tid & 3);

    float accMax = 0.f, accSum = 0.f;
    float arr[16];                       // van Herk: prev-seg suffix / cur h

// Per-row tail: from t[8] (3-row raw sum) compute s, accSum, h, write hbuf.
#define ROWTAIL(T, J, SLOT)                                                    \
    {                                                                          \
        float tl = __shfl_up((T)[7], 1);   if (lane == 0)  tl = 0.f;           \
        float tr = __shfl_down((T)[0], 1); if (lane == 63) tr = 0.f;           \
        float s[8];                                                            \
        s[0] = tl + (T)[0] + (T)[1];                                           \
        _Pragma("unroll") for (int k = 1; k < 7; ++k)                          \
            s[k] = (T)[k - 1] + (T)[k] + (T)[k + 1];                           \
        s[7] = (T)[6] + (T)[7] + tr;                                           \
        const int rlo = ((J) - 8 > y0) ? (J) - 8 : y0;                         \
        const int rhi = ((J) + 8 < y1 - 1) ? (J) + 8 : y1 - 1;                 \
        float rowsum = 0.f;                                                    \
        _Pragma("unroll") for (int k = 0; k < 8; ++k) {                        \
            const int col = c0 + k;                                            \
            const int wlo = (col - 8 > 0) ? col - 8 : 0;                       \
            const int whi = (col + 8 < W - 1) ? col + 8 : W - 1;               \
            rowsum += s[k] * (float)(whi - wlo + 1);                           \
        }                                                                      \
        accSum += rowsum * ((float)(rhi - rlo + 1) * (1.f / 289.f));           \
        float p[8], qarr[8];                                                   \
        p[0] = s[0];                                                           \
        _Pragma("unroll") for (int k = 1; k < 8; ++k)                          \
            p[k] = fmaxf(p[k - 1], s[k]);                                      \
        qarr[7] = s[7];                                                        \
        _Pragma("unroll") for (int k = 6; k >= 0; --k)                         \
            qarr[k] = fmaxf(qarr[k + 1], s[k]);                                \
        const float m = p[7];                                                  \
        float qp[8], pn[8];                                                    \
        _Pragma("unroll") for (int k = 0; k < 8; ++k)                          \
            qp[k] = __shfl_up(qarr[k], 1);                                     \
        _Pragma("unroll") for (int k = 0; k < 8; ++k)                          \
            pn[k] = __shfl_down(p[k], 1);                                      \
        float h[8];                                                            \
        _Pragma("unroll") for (int k = 0; k < 8; ++k) {                        \
            if (lane == 0)  qp[k] = NEG_INF;                                   \
            if (lane == 63) pn[k] = NEG_INF;                                   \
            h[k] = fmaxf(fmaxf(qp[k], m), pn[k]);                              \
        }                                                                      \
        float* hw = hwbase + (SLOT) * W;                                       \
        *(float4*)&hw[lane << 2]         = make_float4(h[0], h[1], h[2], h[3]); \
        *(float4*)&hw[256 + (lane << 2)] = make_float4(h[4], h[5], h[6], h[7]); \
    }

#pragma unroll 1
    for (int b = 0; b < 5; ++b) {        // 5 batches of 16 s-rows = 80 rows
        const int jb = jlo_v + b * 16;
        float* hwbase = &hbuf[b & 1][0][0];

        const int j0 = jb + 2 * w;       // wave's contiguous pair (j0 even)
        const int j1 = j0 + 1;
        if (j0 >= 0 && j0 < H) {         // pair entirely real (never straddles)
            // ---- shared loads: raw rows j0-1 .. j0+2 (4 rows, 8 float4) ----
            float v0[8], v1[8], v2[8], v3[8];
            {
                const float* rp = im + (size_t)j0 * W + c0;        // row j0
                const float4 a = *(const float4*)rp;
                const float4 c4 = *(const float4*)(rp + 4);
                v1[0]=a.x; v1[1]=a.y; v1[2]=a.z; v1[3]=a.w;
                v1[4]=c4.x; v1[5]=c4.y; v1[6]=c4.z; v1[7]=c4.w;
            }
            {
                const float* rp = im + (size_t)j1 * W + c0;        // row j1
                const float4 a = *(const float4*)rp;
                const float4 c4 = *(const float4*)(rp + 4);
                v2[0]=a.x; v2[1]=a.y; v2[2]=a.z; v2[3]=a.w;
                v2[4]=c4.x; v2[5]=c4.y; v2[6]=c4.z; v2[7]=c4.w;
            }
            if (j0 - 1 >= 0) {
                const float* rp = im + (size_t)(j0 - 1) * W + c0;  // row j0-1
                const float4 a = *(const float4*)rp;
                const float4 c4 = *(const float4*)(rp + 4);
                v0[0]=a.x; v0[1]=a.y; v0[2]=a.z; v0[3]=a.w;
                v0[4]=c4.x; v0[5]=c4.y; v0[6]=c4.z; v0[7]=c4.w;
            } else {
#pragma unroll
                for (int k = 0; k < 8; ++k) v0[k] = 0.f;
            }
            if (j1 + 1 < H) {
                const float* rp = im + (size_t)(j1 + 1) * W + c0;  // row j1+1
                const float4 a = *(const float4*)rp;
                const float4 c4 = *(const float4*)(rp + 4);
                v3[0]=a.x; v3[1]=a.y; v3[2]=a.z; v3[3]=a.w;
                v3[4]=c4.x; v3[5]=c4.y; v3[6]=c4.z; v3[7]=c4.w;
            } else {
#pragma unroll
                for (int k = 0; k < 8; ++k) v3[k] = 0.f;
            }
            // ---- shared middle partial: t0 = v0+v1+v2, t1 = v1+v2+v3 ----
            float t0[8], t1[8];
#pragma unroll
            for (int k = 0; k < 8; ++k) {
                const float mid = v1[k] + v2[k];
                t0[k] = v0[k] + mid;
                t1[k] = mid + v3[k];
            }
            ROWTAIL(t0, j0, 2 * w)
            ROWTAIL(t1, j1, 2 * w + 1)
        } else {                         // virtual pair
            const float4 ninf = make_float4(NEG_INF, NEG_INF, NEG_INF, NEG_INF);
            float* hw = hwbase + (2 * w) * W;
            *(float4*)&hw[lane << 2]         = ninf;
            *(float4*)&hw[256 + (lane << 2)] = ninf;
            hw += W;
            *(float4*)&hw[lane << 2]         = ninf;
            *(float4*)&hw[256 + (lane << 2)] = ninf;
        }
        __syncthreads();                  // the ONLY barrier per batch

        // ---- stage C: vertical van Herk over this 16-row segment ----
        const float* hb = hwbase;
        float Pblk = NEG_INF;
        if (b >= 1) {
#pragma unroll
            for (int r = 0; r < 16; ++r) {
                const float hv = hb[r * W + pos];
                Pblk = fmaxf(Pblk, hv);
                accMax += fmaxf(arr[r], Pblk);
                arr[r] = hv;
            }
        } else {
#pragma unroll
            for (int r = 0; r < 16; ++r) {
                const float hv = hb[r * W + pos];
                Pblk = fmaxf(Pblk, hv);
                arr[r] = hv;
            }
        }
        // segment end: in-place suffix transform arr[r] = max(h[r..15])
#pragma unroll
        for (int rr = 14; rr >= 0; --rr) arr[rr] = fmaxf(arr[rr], arr[rr + 1]);
    }
#undef ROWTAIL

    // ---- block reduction (values are 9x-scaled; undo once) ----
    double v = ((double)accMax - (double)accSum) * (1.0 / 9.0);
#pragma unroll
    for (int off = 32; off > 0; off >>= 1) v += __shfl_down(v, off, 64);
    if (lane == 0) wsum[w] = v;
    __syncthreads();
    if (tid == 0) {
        double bsum = 0.0;
#pragma unroll
        for (int wv = 0; wv < 8; ++wv) bsum += wsum[wv];
        atomicAdd(acc, bsum);
    }
}

__global__ void finalize_kernel(const double* __restrict__ acc, float* __restrict__ out) {
    if (threadIdx.x == 0) {
        // total pixels across both tensors = 2*32*512*512 = 16777216
        out[0] = (float)(1.0 - acc[0] * (1.0 / 16777216.0));
    }
}

extern "C" void kernel_launch(void* const* d_in, const int* in_sizes, int n_in,
                              void* d_out, int out_size, void* d_ws, size_t ws_size,
                              hipStream_t stream) {
    const float* in0 = (const float*)d_in[0];
    const float* in1 = (const float*)d_in[1];
    float* out = (float*)d_out;
    double* acc = (double*)d_ws;

    zero_acc_kernel<<<1, 64, 0, stream>>>(acc);
    fused_kernel<<<dim3(NBANDS, 32, 2), 512, 0, stream>>>(in0, in1, acc);
    finalize_kernel<<<1, 64, 0, stream>>>(acc, out);
}

// Round 20
// 31.866 us; speedup vs baseline: 1.3187x; 1.0642x over previous
//
#include <hip/hip_runtime.h>

#define H 512
#define W 512
#define BAND 64
#define NBANDS (H / BAND)   // 8
#define NEG_INF (-3.402823466e38f)

__global__ void zero_acc_kernel(double* acc) {
    if (threadIdx.x == 0) acc[0] = 0.0;
}

// DPP wave shifts (gfx9/CDNA): wave_shr1 (0x138) = shfl_up by 1 with `old` as
// the lane-0 fill; wave_shl1 (0x130) = shfl_down by 1 with `old` as lane-63
// fill. VALU ops -> zero DS-pipe usage (vs ds_bpermute from __shfl).
__device__ __forceinline__ float dpp_up1(float x, float fill) {
    return __int_as_float(__builtin_amdgcn_update_dpp(
        __float_as_int(fill), __float_as_int(x), 0x138, 0xF, 0xF, false));
}
__device__ __forceinline__ float dpp_down1(float x, float fill) {
    return __int_as_float(__builtin_amdgcn_update_dpp(
        __float_as_int(fill), __float_as_int(x), 0x130, 0xF, 0xF, false));
}

// R19 structure (best: 33.9us) + R20 change: all lane+-1 shuffles -> DPP.
// One block per (band of 64 output rows, image, tensor); 512 threads = 8 waves.
// Batches of 16 s-rows; each wave owns slots 2w, 2w+1 (contiguous pair):
// 8 float4 loads/pair (shared halo rows), shared middle partial for the two
// 3-row sums. Per row: s = horizontal 3-sum (9x-scaled) via 2 DPP halos;
// horizontal 17-max via suffix q[8]/prefix p[8] in regs + 16 DPP shifts:
//   h(8L+k) = max(q_{L-1}[k], m_L, p_{L+1}[k]).
// Vertical 17-max: batch == van Herk segment: h rows -> double-buffered hbuf
// (ONE barrier per batch), per-column register van Herk (arr[16]).
// R20 rationale: per-CU pipe sums put DS at ~13us (1440 ds_bpermute
// shuffles/block, the 786K SQ_LDS_BANK_CONFLICT bookkeeping) vs VALU ~9us;
// DPP moves shuffles to VALU, DS/wave/batch 56 -> 20 instrs.
// Lessons: (R12/R13) unroll hoisting + tight cap -> spill ((512,4) + outer
// `#pragma unroll 1`); (R16) extra barrier regressed; (R18) dummy-LDS
// prefetch double-fetched (reverted).
// hbuf split-half layout: k=0..3 at [4L], k=4..7 at [256+4L]; writes and
// column reads conflict-free.
__global__ __launch_bounds__(512, 4) void fused_kernel(const float* __restrict__ in0,
                                                       const float* __restrict__ in1,
                                                       double* __restrict__ acc) {
    const int band = blockIdx.x;
    const int img  = blockIdx.y;
    const float* __restrict__ im = (blockIdx.z ? in1 : in0) + (size_t)img * H * W;

    const int y0 = band * BAND, y1 = y0 + BAND;
    const int jlo_v = y0 - 8;            // first streamed s-row (even)

    __shared__ float hbuf[2][16][W];     // double-buffered h rows (split-half)
    __shared__ double wsum[8];

    const int tid  = threadIdx.x;
    const int w    = tid >> 6;           // wave id 0..7
    const int lane = tid & 63;
    const int c0   = lane << 3;          // 8 cols per lane
    // split-half position of column tid inside an hbuf row
    const int pos  = ((tid & 4) ? 256 : 0) + ((tid >> 3) << 2) + (tid & 3);

    float accMax = 0.f, accSum = 0.f;
    float arr[16];                       // van Herk: prev-seg suffix / cur h

// Per-row tail: from t[8] (3-row raw sum) compute s, accSum, h, write hbuf.
#define ROWTAIL(T, J, SLOT)                                                    \
    {                                                                          \
        const float tl = dpp_up1((T)[7], 0.f);    /* lane0 fill = zero-pad */  \
        const float tr = dpp_down1((T)[0], 0.f);  /* lane63 fill = zero-pad */ \
        float s[8];                                                            \
        s[0] = tl + (T)[0] + (T)[1];                                           \
        _Pragma("unroll") for (int k = 1; k < 7; ++k)                          \
            s[k] = (T)[k - 1] + (T)[k] + (T)[k + 1];                           \
        s[7] = (T)[6] + (T)[7] + tr;                                           \
        const int rlo = ((J) - 8 > y0) ? (J) - 8 : y0;                         \
        const int rhi = ((J) + 8 < y1 - 1) ? (J) + 8 : y1 - 1;                 \
        float rowsum = 0.f;                                                    \
        _Pragma("unroll") for (int k = 0; k < 8; ++k) {                        \
            const int col = c0 + k;                                            \
            const int wlo = (col - 8 > 0) ? col - 8 : 0;                       \
            const int whi = (col + 8 < W - 1) ? col + 8 : W - 1;               \
            rowsum += s[k] * (float)(whi - wlo + 1);                           \
        }                                                                      \
        accSum += rowsum * ((float)(rhi - rlo + 1) * (1.f / 289.f));           \
        float p[8], qarr[8];                                                   \
        p[0] = s[0];                                                           \
        _Pragma("unroll") for (int k = 1; k < 8; ++k)                          \
            p[k] = fmaxf(p[k - 1], s[k]);                                      \
        qarr[7] = s[7];                                                        \
        _Pragma("unroll") for (int k = 6; k >= 0; --k)                         \
            qarr[k] = fmaxf(qarr[k + 1], s[k]);                                \
        const float m = p[7];                                                  \
        float h[8];                                                            \
        _Pragma("unroll") for (int k = 0; k < 8; ++k) {                        \
            const float qp = dpp_up1(qarr[k], NEG_INF);   /* left suffix  */   \
            const float pn = dpp_down1(p[k], NEG_INF);    /* right prefix */   \
            h[k] = fmaxf(fmaxf(qp, m), pn);                                    \
        }                                                                      \
        float* hw = hwbase + (SLOT) * W;                                       \
        *(float4*)&hw[lane << 2]         = make_float4(h[0], h[1], h[2], h[3]); \
        *(float4*)&hw[256 + (lane << 2)] = make_float4(h[4], h[5], h[6], h[7]); \
    }

#pragma unroll 1
    for (int b = 0; b < 5; ++b) {        // 5 batches of 16 s-rows = 80 rows
        const int jb = jlo_v + b * 16;
        float* hwbase = &hbuf[b & 1][0][0];

        const int j0 = jb + 2 * w;       // wave's contiguous pair (j0 even)
        const int j1 = j0 + 1;
        if (j0 >= 0 && j0 < H) {         // pair entirely real (never straddles)
            // ---- shared loads: raw rows j0-1 .. j0+2 (4 rows, 8 float4) ----
            float v0[8], v1[8], v2[8], v3[8];
            {
                const float* rp = im + (size_t)j0 * W + c0;        // row j0
                const float4 a = *(const float4*)rp;
                const float4 c4 = *(const float4*)(rp + 4);
                v1[0]=a.x; v1[1]=a.y; v1[2]=a.z; v1[3]=a.w;
                v1[4]=c4.x; v1[5]=c4.y; v1[6]=c4.z; v1[7]=c4.w;
            }
            {
                const float* rp = im + (size_t)j1 * W + c0;        // row j1
                const float4 a = *(const float4*)rp;
                const float4 c4 = *(const float4*)(rp + 4);
                v2[0]=a.x; v2[1]=a.y; v2[2]=a.z; v2[3]=a.w;
                v2[4]=c4.x; v2[5]=c4.y; v2[6]=c4.z; v2[7]=c4.w;
            }
            if (j0 - 1 >= 0) {
                const float* rp = im + (size_t)(j0 - 1) * W + c0;  // row j0-1
                const float4 a = *(const float4*)rp;
                const float4 c4 = *(const float4*)(rp + 4);
                v0[0]=a.x; v0[1]=a.y; v0[2]=a.z; v0[3]=a.w;
                v0[4]=c4.x; v0[5]=c4.y; v0[6]=c4.z; v0[7]=c4.w;
            } else {
#pragma unroll
                for (int k = 0; k < 8; ++k) v0[k] = 0.f;
            }
            if (j1 + 1 < H) {
                const float* rp = im + (size_t)(j1 + 1) * W + c0;  // row j1+1
                const float4 a = *(const float4*)rp;
                const float4 c4 = *(const float4*)(rp + 4);
                v3[0]=a.x; v3[1]=a.y; v3[2]=a.z; v3[3]=a.w;
                v3[4]=c4.x; v3[5]=c4.y; v3[6]=c4.z; v3[7]=c4.w;
            } else {
#pragma unroll
                for (int k = 0; k < 8; ++k) v3[k] = 0.f;
            }
            // ---- shared middle partial: t0 = v0+v1+v2, t1 = v1+v2+v3 ----
            float t0[8], t1[8];
#pragma unroll
            for (int k = 0; k < 8; ++k) {
                const float mid = v1[k] + v2[k];
                t0[k] = v0[k] + mid;
                t1[k] = mid + v3[k];
            }
            ROWTAIL(t0, j0, 2 * w)
            ROWTAIL(t1, j1, 2 * w + 1)
        } else {                         // virtual pair
            const float4 ninf = make_float4(NEG_INF, NEG_INF, NEG_INF, NEG_INF);
            float* hw = hwbase + (2 * w) * W;
            *(float4*)&hw[lane << 2]         = ninf;
            *(float4*)&hw[256 + (lane << 2)] = ninf;
            hw += W;
            *(float4*)&hw[lane << 2]         = ninf;
            *(float4*)&hw[256 + (lane << 2)] = ninf;
        }
        __syncthreads();                  // the ONLY barrier per batch

        // ---- stage C: vertical van Herk over this 16-row segment ----
        const float* hb = hwbase;
        float Pblk = NEG_INF;
        if (b >= 1) {
#pragma unroll
            for (int r = 0; r < 16; ++r) {
                const float hv = hb[r * W + pos];
                Pblk = fmaxf(Pblk, hv);
                accMax += fmaxf(arr[r], Pblk);
                arr[r] = hv;
            }
        } else {
#pragma unroll
            for (int r = 0; r < 16; ++r) {
                const float hv = hb[r * W + pos];
                Pblk = fmaxf(Pblk, hv);
                arr[r] = hv;
            }
        }
        // segment end: in-place suffix transform arr[r] = max(h[r..15])
#pragma unroll
        for (int rr = 14; rr >= 0; --rr) arr[rr] = fmaxf(arr[rr], arr[rr + 1]);
    }
#undef ROWTAIL

    // ---- block reduction (values are 9x-scaled; undo once) ----
    double v = ((double)accMax - (double)accSum) * (1.0 / 9.0);
#pragma unroll
    for (int off = 32; off > 0; off >>= 1) v += __shfl_down(v, off, 64);
    if (lane == 0) wsum[w] = v;
    __syncthreads();
    if (tid == 0) {
        double bsum = 0.0;
#pragma unroll
        for (int wv = 0; wv < 8; ++wv) bsum += wsum[wv];
        atomicAdd(acc, bsum);
    }
}

__global__ void finalize_kernel(const double* __restrict__ acc, float* __restrict__ out) {
    if (threadIdx.x == 0) {
        // total pixels across both tensors = 2*32*512*512 = 16777216
        out[0] = (float)(1.0 - acc[0] * (1.0 / 16777216.0));
    }
}

extern "C" void kernel_launch(void* const* d_in, const int* in_sizes, int n_in,
                              void* d_out, int out_size, void* d_ws, size_t ws_size,
                              hipStream_t stream) {
    const float* in0 = (const float*)d_in[0];
    const float* in1 = (const float*)d_in[1];
    float* out = (float*)d_out;
    double* acc = (double*)d_ws;

    zero_acc_kernel<<<1, 64, 0, stream>>>(acc);
    fused_kernel<<<dim3(NBANDS, 32, 2), 512, 0, stream>>>(in0, in1, acc);
    finalize_kernel<<<1, 64, 0, stream>>>(acc, out);
}